// Round 14
// baseline (201.545 us; speedup 1.0000x reference)
//
#include <hip/hip_runtime.h>
#include <hip/hip_fp16.h>
#include <math.h>

// ---------------------------------------------------------------------------
// GCN. CSR build = bucketed counting sort, LDS atomics only (no global
// atomics: device-scope atomic-returns run memory-side at ~23 Gops/s on
// multi-XCD CDNA4 — measured R3/R4). ebuf packed (src<<7|local) in 4 B.
// t' = dinv[row] * (row @ W) (scaled in mm epilogue) so
//   agg[d] = relu(b + dinv[d] * (sum_e t'[src_e] + t'[d]))
// colw stores ONLY src (4 B); gather inner loop is pure packed-fp16 adds
// (v_pk_add_f16), unrolled x8 for MLP; fp32 epilogue.
// R13: p1 at TPB=1024, 128-node buckets (p2 ~3 blocks/CU).
// REVERTED experiments: R10 gather-GEMM fusion (occupancy), R12 degree-perm
// (scattered agg writes cost more than divergence saved).
// ---------------------------------------------------------------------------

#define TPB    256
#define TPB1   1024         // pass-1 block size (occupancy)
#define EBLKS  256          // pass-1 edge blocks
#define BSH    7            // 128 nodes per bucket
#define BNODES (1 << BSH)

// P1a: OFS[c*EBLKS + b] = #edges of bucket c in block b's chunk
__global__ __launch_bounds__(TPB1)
void k_p1hist(const int* __restrict__ dst, int* __restrict__ OFS,
              int E, int CH, int NBC) {
    __shared__ int h[1024];
    int tid = threadIdx.x, b = blockIdx.x;
    h[tid] = 0;
    __syncthreads();
    int beg = b * CH, end = min(E, beg + CH);
    if (beg < end) {
        int nfull = (end - beg) & ~3;
        for (int i = beg + tid * 4; i < beg + nfull; i += TPB1 * 4) {
            int4 d = *(const int4*)&dst[i];
            atomicAdd(&h[d.x >> BSH], 1);
            atomicAdd(&h[d.y >> BSH], 1);
            atomicAdd(&h[d.z >> BSH], 1);
            atomicAdd(&h[d.w >> BSH], 1);
        }
        if (tid < (end - beg) - nfull)
            atomicAdd(&h[dst[beg + nfull + tid] >> BSH], 1);
    }
    __syncthreads();
    for (int c = tid; c < NBC; c += TPB1) OFS[c * EBLKS + b] = h[c];
}

// scanA: per-block sums (1024 elems/block) of OFS
__global__ __launch_bounds__(TPB)
void k_scanA(const int* __restrict__ OFS, int* __restrict__ bsum, int total) {
    __shared__ int s[TPB];
    int tid = threadIdx.x;
    int i0  = blockIdx.x * 1024 + tid * 4;
    int t = 0;
#pragma unroll
    for (int k = 0; k < 4; ++k) {
        int i = i0 + k;
        t += (i < total) ? OFS[i] : 0;
    }
    s[tid] = t;
    __syncthreads();
    for (int off = TPB / 2; off > 0; off >>= 1) {
        if (tid < off) s[tid] += s[tid + off];
        __syncthreads();
    }
    if (tid == 0) bsum[blockIdx.x] = s[0];
}

// scanC: exclusive scan; each block sums bsum[0..blockIdx) via a looped
// 64-lane reduction (works for any NBLK).
__global__ __launch_bounds__(TPB)
void k_scanC(int* __restrict__ OFS, const int* __restrict__ bsum, int total) {
    __shared__ int s[TPB];
    __shared__ int pfx;
    int tid = threadIdx.x;
    if (tid < 64) {
        int v = 0;
        for (int j = tid; j < (int)blockIdx.x; j += 64) v += bsum[j];
#pragma unroll
        for (int off = 1; off < 64; off <<= 1) v += __shfl_xor(v, off);
        if (tid == 0) pfx = v;
    }
    int i0 = blockIdx.x * 1024 + tid * 4;
    int v[4];
#pragma unroll
    for (int k = 0; k < 4; ++k) {
        int i = i0 + k;
        v[k] = (i < total) ? OFS[i] : 0;
    }
    int tsum = v[0] + v[1] + v[2] + v[3];
    s[tid] = tsum;
    __syncthreads();
    for (int off = 1; off < TPB; off <<= 1) {
        int x = (tid >= off) ? s[tid - off] : 0;
        __syncthreads();
        s[tid] += x;
        __syncthreads();
    }
    int base = pfx + (s[tid] - tsum);
#pragma unroll
    for (int k = 0; k < 4; ++k) {
        int i = i0 + k;
        if (i < total) {
            OFS[i] = base;
            base += v[k];
        }
    }
}

// P1c: scatter packed (src<<7|local) into bucket-contiguous ebuf (LDS cursors)
__global__ __launch_bounds__(TPB1)
void k_p1scatter(const int* __restrict__ src, const int* __restrict__ dst,
                 const int* __restrict__ OFS, int* __restrict__ ebuf,
                 int E, int CH, int NBC) {
    __shared__ int cur[1024];
    int tid = threadIdx.x, b = blockIdx.x;
    for (int c = tid; c < NBC; c += TPB1) cur[c] = OFS[c * EBLKS + b];
    __syncthreads();
    int beg = b * CH, end = min(E, beg + CH);
    if (beg >= end) return;
    int nfull = (end - beg) & ~3;
    for (int i = beg + tid * 4; i < beg + nfull; i += TPB1 * 4) {
        int4 s4 = *(const int4*)&src[i];
        int4 d4 = *(const int4*)&dst[i];
        int p0 = atomicAdd(&cur[d4.x >> BSH], 1);
        int p1 = atomicAdd(&cur[d4.y >> BSH], 1);
        int p2 = atomicAdd(&cur[d4.z >> BSH], 1);
        int p3 = atomicAdd(&cur[d4.w >> BSH], 1);
        ebuf[p0] = (s4.x << BSH) | (d4.x & (BNODES - 1));
        ebuf[p1] = (s4.y << BSH) | (d4.y & (BNODES - 1));
        ebuf[p2] = (s4.z << BSH) | (d4.z & (BNODES - 1));
        ebuf[p3] = (s4.w << BSH) | (d4.w & (BNODES - 1));
    }
    if (tid < (end - beg) - nfull) {
        int i = beg + nfull + tid;
        int d = dst[i];
        int p = atomicAdd(&cur[d >> BSH], 1);
        ebuf[p] = (src[i] << BSH) | (d & (BNODES - 1));
    }
}

// P2 (fused): per 128-node bucket: LDS hist -> scan -> row_ptr/dinv + LDS
// start offsets; then rank pass -> colw[ofs+rank] = src.
__global__ __launch_bounds__(TPB)
void k_p2(const int* __restrict__ ebuf, const int* __restrict__ OFS,
          int* __restrict__ row_ptr, float* __restrict__ dinv,
          int* __restrict__ colw, int N, int E, int NBC) {
    __shared__ int cnt[BNODES];
    __shared__ int ofs[BNODES];
    __shared__ int s1[TPB];
    int tid = threadIdx.x, c = blockIdx.x;
    int beg = OFS[c * EBLKS];
    int end = (c == NBC - 1) ? E : OFS[(c + 1) * EBLKS];
    if (tid < BNODES) cnt[tid] = 0;
    __syncthreads();
    for (int i = beg + tid; i < end; i += TPB)
        atomicAdd(&cnt[ebuf[i] & (BNODES - 1)], 1);
    __syncthreads();
    int a = (tid < BNODES) ? cnt[tid] : 0;
    s1[tid] = a;
    __syncthreads();
    for (int off = 1; off < TPB; off <<= 1) {
        int x = (tid >= off) ? s1[tid - off] : 0;
        __syncthreads();
        s1[tid] += x;
        __syncthreads();
    }
    int ex = s1[tid] - a;   // exclusive
    if (tid < BNODES) {
        int node = (c << BSH) + tid;
        ofs[tid] = beg + ex;
        if (node < N) {
            row_ptr[node] = beg + ex;
            dinv[node]    = rsqrtf((float)(a + 1));
        }
        cnt[tid] = 0;       // reset for rank pass
    }
    if (c == NBC - 1 && tid == 0) row_ptr[N] = E;
    __syncthreads();
    // rank + fill (colw = src only)
    for (int i0 = beg + tid; i0 < end; i0 += TPB * 4) {
        int sv[4], dl[4], pos[4];
        int have = 0;
#pragma unroll
        for (int k = 0; k < 4; ++k) {
            int i = i0 + k * TPB;
            if (i < end) {
                int e = ebuf[i];
                sv[k] = e >> BSH;
                dl[k] = e & (BNODES - 1);
                have = k + 1;
            }
        }
#pragma unroll
        for (int k = 0; k < 4; ++k) {
            if (k < have) {
                int r  = atomicAdd(&cnt[dl[k]], 1);
                pos[k] = ofs[dl[k]] + r;
            }
        }
#pragma unroll
        for (int k = 0; k < 4; ++k)
            if (k < have) colw[pos[k]] = sv[k];
    }
}

// Dense GEMM: [n,64] @ [64,F].
// !FINAL: out = fp16 t' = dinv[row]*(row@W); also writes zero sentinel row n.
// FINAL:  out = fp32 row@W + bias.
// HIN: input rows fp16, else fp32.
template <int F, bool FINAL, bool HIN>
__launch_bounds__(256)
__global__ void k_mm(const void* __restrict__ in, const float* __restrict__ W,
                     const float* __restrict__ bias, const float* __restrict__ dinv,
                     void* __restrict__ out, int n) {
    __shared__ float in_s[64 * 68];
    __shared__ float w_s[64 * F];

    const int tid  = threadIdx.x;
    const int row0 = blockIdx.x * 64;

    for (int i4 = tid; i4 < (64 * F) / 4; i4 += 256)
        ((float4*)w_s)[i4] = ((const float4*)W)[i4];

    if constexpr (HIN) {
        for (int idx = tid; idx < 64 * 8; idx += 256) {
            int r  = idx >> 3;
            int c8 = idx & 7;
            uint4 u = make_uint4(0u, 0u, 0u, 0u);
            if (row0 + r < n)
                u = *(const uint4*)((const __half*)in + (size_t)(row0 + r) * 64 + c8 * 8);
            float2 f0 = __half22float2(*(__half2*)&u.x);
            float2 f1 = __half22float2(*(__half2*)&u.y);
            float2 f2 = __half22float2(*(__half2*)&u.z);
            float2 f3 = __half22float2(*(__half2*)&u.w);
            float* o = &in_s[r * 68 + c8 * 8];
            *(float4*)&o[0] = make_float4(f0.x, f0.y, f1.x, f1.y);
            *(float4*)&o[4] = make_float4(f2.x, f2.y, f3.x, f3.y);
        }
    } else {
        for (int idx = tid; idx < 64 * 16; idx += 256) {
            int r  = idx >> 4;
            int c4 = idx & 15;
            float4 v;
            if (row0 + r < n)
                v = *(const float4*)((const float*)in + (size_t)(row0 + r) * 64 + c4 * 4);
            else
                v = make_float4(0.f, 0.f, 0.f, 0.f);
            *(float4*)&in_s[r * 68 + c4 * 4] = v;
        }
    }
    __syncthreads();

    constexpr int CPT = F / 16;
    const int tx = tid & 15;
    const int ty = tid >> 4;

    float acc[4][CPT];
#pragma unroll
    for (int r = 0; r < 4; ++r)
#pragma unroll
        for (int c = 0; c < CPT; ++c) acc[r][c] = 0.f;

#pragma unroll 4
    for (int k = 0; k < 64; ++k) {
        float b[CPT];
#pragma unroll
        for (int c = 0; c < CPT; ++c) b[c] = w_s[k * F + tx * CPT + c];
#pragma unroll
        for (int r = 0; r < 4; ++r) {
            float a = in_s[(ty * 4 + r) * 68 + k];
#pragma unroll
            for (int c = 0; c < CPT; ++c) acc[r][c] = fmaf(a, b[c], acc[r][c]);
        }
    }

#pragma unroll
    for (int r = 0; r < 4; ++r) {
        int row = row0 + ty * 4 + r;
        if (row >= n) continue;
        if constexpr (FINAL) {
#pragma unroll
            for (int c = 0; c < CPT; ++c) {
                int col = tx * CPT + c;
                ((float*)out)[(size_t)row * F + col] = acc[r][c] + bias[col];
            }
        } else {
            float dd = dinv[row];
            __half2 p0 = __floats2half2_rn(acc[r][0] * dd, acc[r][1] * dd);
            __half2 p1 = __floats2half2_rn(acc[r][2] * dd, acc[r][3] * dd);
            uint2 u = make_uint2(*(unsigned*)&p0, *(unsigned*)&p1);
            *(uint2*)((__half*)out + (size_t)row * 64 + tx * 4) = u;
        }
    }
    if constexpr (!FINAL) {
        // zero sentinel row n (tail edges in gather read it)
        if (blockIdx.x == 0 && tid < 16)
            *(uint2*)((__half*)out + (size_t)n * 64 + tid * 4) = make_uint2(0u, 0u);
    }
}

// Gather: 8 nodes/wave, 8 lanes/node; edge loop unrolled x8 (8 independent
// 16B row loads in flight); packed fp16 accumulate (v_pk_add_f16), fp32
// epilogue: agg[d] = relu(bias + dinv[d]*(sum_e t'[src_e] + t'[d])).
__global__ __launch_bounds__(256)
void k_gather(const int* __restrict__ row_ptr, const int* __restrict__ colw,
              const float* __restrict__ dinv, const float* __restrict__ bias,
              const __half* __restrict__ t, __half* __restrict__ agg, int N) {
    int tid  = threadIdx.x;
    int wv   = tid >> 6;
    int lane = tid & 63;
    int g = lane >> 3;
    int p = lane & 7;
    int d = blockIdx.x * 32 + wv * 8 + g;

    int beg = 0, end = 0;
    if (d < N) { beg = row_ptr[d]; end = row_ptr[d + 1]; }

    __half2 acc[4];
    acc[0] = acc[1] = acc[2] = acc[3] = __floats2half2_rn(0.f, 0.f);

    for (int e = beg; e < end; e += 8) {
        int s[8];
#pragma unroll
        for (int k = 0; k < 8; ++k)
            s[k] = (e + k < end) ? colw[e + k] : N;   // N = zero sentinel row
        uint4 a[8];
#pragma unroll
        for (int k = 0; k < 8; ++k)
            a[k] = *(const uint4*)(t + (size_t)s[k] * 64 + p * 8);
#pragma unroll
        for (int k = 0; k < 8; ++k) {
            acc[0] = __hadd2(acc[0], *(__half2*)&a[k].x);
            acc[1] = __hadd2(acc[1], *(__half2*)&a[k].y);
            acc[2] = __hadd2(acc[2], *(__half2*)&a[k].z);
            acc[3] = __hadd2(acc[3], *(__half2*)&a[k].w);
        }
    }

    if (d < N) {
        float dd = dinv[d];
        uint4 a = *(const uint4*)(t + (size_t)d * 64 + p * 8);
        float4 b0 = *(const float4*)&bias[p * 8];
        float4 b1 = *(const float4*)&bias[p * 8 + 4];
        float2 s0 = __half22float2(*(__half2*)&a.x);
        float2 s1 = __half22float2(*(__half2*)&a.y);
        float2 s2 = __half22float2(*(__half2*)&a.z);
        float2 s3 = __half22float2(*(__half2*)&a.w);
        float2 c0 = __half22float2(acc[0]);
        float2 c1 = __half22float2(acc[1]);
        float2 c2 = __half22float2(acc[2]);
        float2 c3 = __half22float2(acc[3]);
        float o0 = fmaxf(fmaf(dd, c0.x + s0.x, b0.x), 0.f);
        float o1 = fmaxf(fmaf(dd, c0.y + s0.y, b0.y), 0.f);
        float o2 = fmaxf(fmaf(dd, c1.x + s1.x, b0.z), 0.f);
        float o3 = fmaxf(fmaf(dd, c1.y + s1.y, b0.w), 0.f);
        float o4 = fmaxf(fmaf(dd, c2.x + s2.x, b1.x), 0.f);
        float o5 = fmaxf(fmaf(dd, c2.y + s2.y, b1.y), 0.f);
        float o6 = fmaxf(fmaf(dd, c3.x + s3.x, b1.z), 0.f);
        float o7 = fmaxf(fmaf(dd, c3.y + s3.y, b1.w), 0.f);
        __half2 h0 = __floats2half2_rn(o0, o1);
        __half2 h1 = __floats2half2_rn(o2, o3);
        __half2 h2 = __floats2half2_rn(o4, o5);
        __half2 h3 = __floats2half2_rn(o6, o7);
        uint4 u = make_uint4(*(unsigned*)&h0, *(unsigned*)&h1,
                             *(unsigned*)&h2, *(unsigned*)&h3);
        *(uint4*)(agg + (size_t)d * 64 + p * 8) = u;
    }
}

extern "C" void kernel_launch(void* const* d_in, const int* in_sizes, int n_in,
                              void* d_out, int out_size, void* d_ws, size_t ws_size,
                              hipStream_t stream) {
    const float* x  = (const float*)d_in[0];
    const int*   ei = (const int*)d_in[1];
    const float* W1 = (const float*)d_in[2];
    const float* b1 = (const float*)d_in[3];
    const float* W2 = (const float*)d_in[4];
    const float* b2 = (const float*)d_in[5];
    const float* Wl = (const float*)d_in[6];
    const float* bl = (const float*)d_in[7];
    float*       out = (float*)d_out;

    const int N = in_sizes[0] / 64;
    const int E = in_sizes[1] / 2;
    const int* srcp = ei;
    const int* dstp = ei + E;

    const int NBC   = (N + BNODES - 1) / BNODES;             // buckets (782)
    const int CH    = (((E + EBLKS - 1) / EBLKS) + 3) & ~3;  // chunk, mult of 4
    const int total = NBC * EBLKS;                           // offset matrix
    const int NBLK  = (total + 1023) / 1024;                 // scan blocks

    char*  ws  = (char*)d_ws;
    size_t off = 0;
    auto alloc = [&](size_t bytes) -> void* {
        void* p = (void*)(ws + off);
        off += (bytes + 255) & ~(size_t)255;
        return p;
    };
    int*    OFS     = (int*)alloc(((size_t)total + 1) * 4);
    int*    bsum    = (int*)alloc((size_t)NBLK * 4);
    int*    ebuf    = (int*)alloc((size_t)E * 4);
    int*    row_ptr = (int*)alloc((size_t)(N + 1) * 4);
    float*  dinv    = (float*)alloc((size_t)N * 4);
    int*    colw    = (int*)alloc((size_t)E * 4);
    __half* t1      = (__half*)alloc((size_t)(N + 1) * 64 * 2);  // +sentinel
    __half* agg1    = (__half*)alloc((size_t)N * 64 * 2);
    __half* t2      = t1;    // safe: t1 dead once gather1 consumed it
    __half* agg2    = agg1;  // safe: agg1 dead once mm2 wrote t2

    const int nb_mm = (N + 63) / 64;
    const int nb_g  = (N + 31) / 32;

    // --- CSR build (no global atomics) ---
    k_p1hist   <<<EBLKS, TPB1, 0, stream>>>(dstp, OFS, E, CH, NBC);
    k_scanA    <<<NBLK,  TPB,  0, stream>>>(OFS, bsum, total);
    k_scanC    <<<NBLK,  TPB,  0, stream>>>(OFS, bsum, total);
    k_p1scatter<<<EBLKS, TPB1, 0, stream>>>(srcp, dstp, OFS, ebuf, E, CH, NBC);
    k_p2       <<<NBC,   TPB,  0, stream>>>(ebuf, OFS, row_ptr, dinv, colw, N, E, NBC);

    // --- layer 1: t1' = dinv * (x @ W1) ---
    k_mm<64, false, false><<<nb_mm, 256, 0, stream>>>(x, W1, nullptr, dinv, t1, N);
    k_gather<<<nb_g, 256, 0, stream>>>(row_ptr, colw, dinv, b1, t1, agg1, N);

    // --- layer 2: t2' = dinv * (agg1 @ W2) ---
    k_mm<64, false, true><<<nb_mm, 256, 0, stream>>>(agg1, W2, nullptr, dinv, t2, N);
    k_gather<<<nb_g, 256, 0, stream>>>(row_ptr, colw, dinv, b2, t2, agg2, N);

    // --- head ---
    k_mm<32, true, true><<<nb_mm, 256, 0, stream>>>(agg2, Wl, bl, nullptr, out, N);
}